// Round 2
// 679.845 us; speedup vs baseline: 1.1511x; 1.1511x over previous
//
#include <hip/hip_runtime.h>
#include <math.h>

#define T_CLS 4096
#define V_SZ  4096
#define FW    5
#define S_LEN 512
#define P_TOT 32768          // B*S = 64*512
#define WROW  20480          // V_SZ * FW floats = 80 KB per t-row
#define TT    64             // t's per chunk (per block)
#define NCH   (T_CLS / TT)   // 64 chunks
#define NPC   4              // position chunks
#define PPB   (P_TOT / NPC)  // 8192 positions per block
#define THR   512
// half-ulp of lse (lse in [8,16) -> ulp 2^-20): fp32 log_softmax tie band
#define HALF_ULP 4.76837158203125e-7

typedef const __attribute__((address_space(1))) void* gas_t;
typedef __attribute__((address_space(3))) void* las_t;

// =====================================================================
// fused kernel: gather-logits + online sum-exp + top-2, no logits buffer.
// LDS double buffer, split layout per buffer b (byte base b*81920):
//   [0,65536)      float4 table: entry v at v*16 = W[t][v][0..3]
//   [65536,81920)  scalar table: entry v at v*4  = W[t][v][4]
// Staged with global_load_lds: f4 part reads 16B at 20B stride (4B-aligned),
// scalar part reads 4B. 2 x 80KB = 163840 B = exactly 160 KiB.
// Each thread owns 16 contiguous positions (16 | 512: no row crossing),
// sliding 5-token window, 2 LDS ops per token. Padding handled by x{0,1}
// flags on the 4 compile-time edge slots (exact +0.0 like numpy).
// =====================================================================
__global__ __launch_bounds__(THR, 2) void k_fused(
    const float* __restrict__ W, const float* __restrict__ bias,
    const int* __restrict__ tok,
    float* __restrict__ sA, float* __restrict__ wA,
    float* __restrict__ c0xA, int* __restrict__ c0tA,
    float* __restrict__ c1xA, int* __restrict__ c1tA) {
    __shared__ __align__(16) float lds[40960];          // 163840 B
    char* ldsc = (char*)lds;
    const int tid = threadIdx.x;
    const int chunk = blockIdx.x;
    const int t0 = chunk * TT;
    const int p0 = blockIdx.y * PPB + tid * 16;
    const int s0 = p0 & (S_LEN - 1);
    const int tokbase = p0 - s0;

    // per-thread window token offsets (bytes into f4 table), once
    int voff[20];
#pragma unroll
    for (int idx = 0; idx < 20; ++idx) {
        const int j = s0 - 2 + idx;
        const int jc = min(max(j, 0), S_LEN - 1);
        voff[idx] = tok[tokbase + jc] << 4;
    }
    const float fa = (s0 == 0) ? 0.0f : 1.0f;            // idx 0,1 invalid
    const float fb = (s0 == S_LEN - 16) ? 0.0f : 1.0f;   // idx 18,19 invalid

    float sAcc[16], wAcc[16], c0x[16], c1x[16];
    int c0t[16], c1t[16];
#pragma unroll
    for (int o = 0; o < 16; ++o) {
        sAcc[o] = 0.f; wAcc[o] = 0.f;
        c0x[o] = -INFINITY; c1x[o] = -INFINITY;
        c0t[o] = 0x7fffffff; c1t[o] = 0x7fffffff;
    }

    // prologue: stage row t0 into buffer 0
    {
        const char* row = (const char*)(W + (size_t)t0 * WROW);
#pragma unroll
        for (int j = 0; j < 8; ++j) {
            const int l = j * THR + tid;
            __builtin_amdgcn_global_load_lds((gas_t)(row + 20 * l),
                                             (las_t)(ldsc + 16 * l), 16, 0, 0);
        }
#pragma unroll
        for (int j = 0; j < 8; ++j) {
            const int l = j * THR + tid;
            __builtin_amdgcn_global_load_lds((gas_t)(row + 20 * l + 16),
                                             (las_t)(ldsc + 65536 + 4 * l), 4, 0, 0);
        }
    }
    asm volatile("s_waitcnt vmcnt(0)" ::: "memory");
    __syncthreads();

    for (int i = 0; i < TT; ++i) {
        // issue async stage of next row into the other buffer
        if (i + 1 < TT) {
            const int bb = ((i + 1) & 1) * 81920;
            const char* row = (const char*)(W + (size_t)(t0 + i + 1) * WROW);
#pragma unroll
            for (int j = 0; j < 8; ++j) {
                const int l = j * THR + tid;
                __builtin_amdgcn_global_load_lds((gas_t)(row + 20 * l),
                                                 (las_t)(ldsc + bb + 16 * l), 16, 0, 0);
            }
#pragma unroll
            for (int j = 0; j < 8; ++j) {
                const int l = j * THR + tid;
                __builtin_amdgcn_global_load_lds((gas_t)(row + 20 * l + 16),
                                                 (las_t)(ldsc + bb + 65536 + 4 * l), 4, 0, 0);
            }
        }
        const int fb4 = (i & 1) * 81920;
        const int fbS = fb4 + 65536;
        const int tg = t0 + i;
        const float bt = bias[tg];

        float win[5][5];                                 // rotating token window
#pragma unroll
        for (int idx = 0; idx < 20; ++idx) {
            const float4 a = *(const float4*)(ldsc + fb4 + voff[idx]);
            float e4 = *(const float*)(ldsc + fbS + (voff[idx] >> 2));
            float ax = a.x, ay = a.y, az = a.z, aw = a.w;
            if (idx < 2)   { ax *= fa; ay *= fa; az *= fa; aw *= fa; e4 *= fa; }
            if (idx >= 18) { ax *= fb; ay *= fb; az *= fb; aw *= fb; e4 *= fb; }
#pragma unroll
            for (int s = 0; s < 4; ++s) {
                win[s][0] = win[s+1][0]; win[s][1] = win[s+1][1];
                win[s][2] = win[s+1][2]; win[s][3] = win[s+1][3];
                win[s][4] = win[s+1][4];
            }
            win[4][0] = ax; win[4][1] = ay; win[4][2] = az;
            win[4][3] = aw; win[4][4] = e4;
            if (idx >= 4) {
                // numpy-exact order: b + k0 + k1 + k2 + k3 + k4
                float acc = bt;
                acc += win[0][0]; acc += win[1][1]; acc += win[2][2];
                acc += win[3][3]; acc += win[4][4];
                const int o = idx - 4;
                const float e = __expf(acc);
                sAcc[o] += e;
                wAcc[o] = fmaf(e, acc, wAcc[o]);
                if (acc > c0x[o])      { c1x[o] = c0x[o]; c1t[o] = c0t[o];
                                         c0x[o] = acc;    c0t[o] = tg; }
                else if (acc > c1x[o]) { c1x[o] = acc;    c1t[o] = tg; }
            }
        }
        asm volatile("s_waitcnt vmcnt(0)" ::: "memory");
        __syncthreads();
    }

    // write per-(chunk, position) online state, coalesced float4
    const size_t i0 = (size_t)chunk * P_TOT + p0;
#pragma unroll
    for (int q = 0; q < 4; ++q) {
        *(float4*)(sA  + i0 + 4*q) = make_float4(sAcc[4*q], sAcc[4*q+1], sAcc[4*q+2], sAcc[4*q+3]);
        *(float4*)(wA  + i0 + 4*q) = make_float4(wAcc[4*q], wAcc[4*q+1], wAcc[4*q+2], wAcc[4*q+3]);
        *(float4*)(c0xA + i0 + 4*q) = make_float4(c0x[4*q], c0x[4*q+1], c0x[4*q+2], c0x[4*q+3]);
        *(int4*)(c0tA + i0 + 4*q)   = make_int4(c0t[4*q], c0t[4*q+1], c0t[4*q+2], c0t[4*q+3]);
        *(float4*)(c1xA + i0 + 4*q) = make_float4(c1x[4*q], c1x[4*q+1], c1x[4*q+2], c1x[4*q+3]);
        *(int4*)(c1tA + i0 + 4*q)   = make_int4(c1t[4*q], c1t[4*q+1], c1t[4*q+2], c1t[4*q+3]);
    }
}

// =====================================================================
// merge chunks, band argmax, outputs, partial entropy
// =====================================================================
__global__ __launch_bounds__(256) void k_final(const float* __restrict__ sA,
                                               const float* __restrict__ wA,
                                               const float* __restrict__ c0xA,
                                               const int* __restrict__ c0tA,
                                               const float* __restrict__ c1xA,
                                               const int* __restrict__ c1tA,
                                               float* __restrict__ out,
                                               float* __restrict__ partial) {
    const int p = blockIdx.x * 256 + threadIdx.x;
    float S = 0.f, Wm = 0.f, m = -INFINITY;
    for (int g = 0; g < NCH; g++) {
        const int i = g * P_TOT + p;
        S += sA[i]; Wm += wA[i];
        m = fmaxf(m, c0xA[i]);
    }
    int am = 0x7fffffff; float xam = m;
    for (int g = 0; g < NCH; g++) {
        const int i = g * P_TOT + p;
        const float x0 = c0xA[i]; const int t0c = c0tA[i];
        if ((double)m - (double)x0 < HALF_ULP && t0c < am) { am = t0c; xam = x0; }
        const float x1 = c1xA[i]; const int t1c = c1tA[i];
        if ((double)m - (double)x1 < HALF_ULP && t1c < am) { am = t1c; xam = x1; }
    }
    const float ls = logf(S);
    out[p] = (float)am;
    out[P_TOT + p] = xam - ls;          // log_softmax at argmax
    const float H = ls - Wm / S;        // per-position entropy

    __shared__ float red[256];
    red[threadIdx.x] = H;
    __syncthreads();
    for (int off = 128; off > 0; off >>= 1) {
        if (threadIdx.x < off) red[threadIdx.x] += red[threadIdx.x + off];
        __syncthreads();
    }
    if (threadIdx.x == 0) partial[blockIdx.x] = red[0];
}

__global__ __launch_bounds__(128) void k_entropy(const float* __restrict__ partial,
                                                 float* __restrict__ out) {
    __shared__ float red[128];
    red[threadIdx.x] = partial[threadIdx.x];
    __syncthreads();
    for (int off = 64; off > 0; off >>= 1) {
        if (threadIdx.x < off) red[threadIdx.x] += red[threadIdx.x + off];
        __syncthreads();
    }
    if (threadIdx.x == 0)
        out[2 * P_TOT] = red[0] / ((float)P_TOT * (float)T_CLS);
}

// ---------------- fallback (tiny workspace) ----------------------------------
__global__ void k_zero1(float* p) { *p = 0.0f; }
__global__ void k_scale1(float* p) { *p = *p / ((float)P_TOT * (float)T_CLS); }

__device__ inline void cand_init(float* cx, int* ct) {
#pragma unroll
    for (int j = 0; j < 4; j++) { cx[j] = -INFINITY; ct[j] = 0x7fffffff; }
}
__device__ inline void cand_insert(float* cx, int* ct, float x, int t) {
    if (!(x > cx[3])) return;
    if (x > cx[0]) {
        cx[3]=cx[2]; ct[3]=ct[2]; cx[2]=cx[1]; ct[2]=ct[1];
        cx[1]=cx[0]; ct[1]=ct[0]; cx[0]=x; ct[0]=t;
    } else if (x > cx[1]) {
        cx[3]=cx[2]; ct[3]=ct[2]; cx[2]=cx[1]; ct[2]=ct[1]; cx[1]=x; ct[1]=t;
    } else if (x > cx[2]) {
        cx[3]=cx[2]; ct[3]=ct[2]; cx[2]=x; ct[2]=t;
    } else { cx[3]=x; ct[3]=t; }
}
__device__ inline void cand_merge(float* ax, int* at, const float* bx, const int* bt) {
    float rx[4]; int rt[4]; int i = 0, j = 0;
#pragma unroll
    for (int k = 0; k < 4; k++) {
        const bool ta = (ax[i] > bx[j]) || (ax[i] == bx[j] && at[i] < bt[j]);
        if (ta) { rx[k] = ax[i]; rt[k] = at[i]; i++; }
        else    { rx[k] = bx[j]; rt[k] = bt[j]; j++; }
    }
#pragma unroll
    for (int k = 0; k < 4; k++) { ax[k] = rx[k]; at[k] = rt[k]; }
}
__device__ inline int band_argmax(const float* cx, const int* ct) {
    const double m = (double)cx[0];
    int am = ct[0];
#pragma unroll
    for (int j = 1; j < 4; j++)
        if (m - (double)cx[j] < HALF_ULP && ct[j] < am) am = ct[j];
    return am;
}

__global__ __launch_bounds__(64) void k_fallback(const float* __restrict__ W,
                                                 const float* __restrict__ bias,
                                                 const int* __restrict__ tok,
                                                 float* __restrict__ out) {
    const int p = blockIdx.x;
    const int srow = p & (S_LEN - 1);
    const int rowbase = p - srow;
    int vtok[FW]; bool val[FW];
#pragma unroll
    for (int k = 0; k < FW; k++) {
        const int ss = srow + k - 2;
        val[k] = ((unsigned)ss < (unsigned)S_LEN);
        vtok[k] = val[k] ? tok[rowbase + ss] : 0;
    }
    float s = 0.f, w = 0.f, cx[4]; int ct[4];
    cand_init(cx, ct);
    for (int t = threadIdx.x; t < T_CLS; t += 64) {
        const float* wr = W + (size_t)t * WROW;
        float acc = bias[t];
#pragma unroll
        for (int k = 0; k < FW; k++)
            if (val[k]) acc += wr[vtok[k] * FW + k];
        const float e = __expf(acc);
        s += e; w = fmaf(e, acc, w);
        cand_insert(cx, ct, acc, t);
    }
    for (int off = 32; off > 0; off >>= 1) {
        float ox[4]; int ot[4];
#pragma unroll
        for (int j = 0; j < 4; j++) { ox[j] = __shfl_down(cx[j], off); ot[j] = __shfl_down(ct[j], off); }
        const float os = __shfl_down(s, off);
        const float ow = __shfl_down(w, off);
        cand_merge(cx, ct, ox, ot);
        s += os; w += ow;
    }
    if (threadIdx.x == 0) {
        const int am = band_argmax(cx, ct);
        const float ls = logf(s);
        out[p] = (float)am;
        out[P_TOT + p] = cx[0] - ls;
        atomicAdd(&out[2 * P_TOT], ls - w / s);
    }
}

extern "C" void kernel_launch(void* const* d_in, const int* in_sizes, int n_in,
                              void* d_out, int out_size, void* d_ws, size_t ws_size,
                              hipStream_t stream) {
    const float* W    = (const float*)d_in[0];
    const float* bias = (const float*)d_in[1];
    const int*   tok  = (const int*)d_in[2];
    float* out = (float*)d_out;

    const size_t NS = (size_t)NCH * P_TOT;            // 2M entries per array
    const size_t stateBytes = NS * 4 * 6;             // s,w,c0x,c0t,c1x,c1t = 48 MB
    const size_t partialBytes = 1024 * 4;

    if (ws_size < stateBytes + partialBytes) {
        k_zero1<<<1, 1, 0, stream>>>(out + 2 * P_TOT);
        k_fallback<<<dim3(P_TOT), dim3(64), 0, stream>>>(W, bias, tok, out);
        k_scale1<<<1, 1, 0, stream>>>(out + 2 * P_TOT);
        return;
    }

    float* sA  = (float*)d_ws;
    float* wA  = sA + NS;
    float* c0x = wA + NS;
    int*   c0t = (int*)(c0x + NS);
    float* c1x = (float*)(c0t + NS);
    int*   c1t = (int*)(c1x + NS);
    float* partial = (float*)(c1t + NS);

    // grid: x = t-chunk (64), y = p-chunk (4). 256 blocks = 1/CU, one round.
    // Siblings of a t-chunk are 64 apart in linear id -> same id%8 -> same XCD
    // -> W row fetched from HBM once, siblings hit L2/L3.
    k_fused<<<dim3(NCH, NPC), dim3(THR), 0, stream>>>(W, bias, tok,
                                                      sA, wA, c0x, c0t, c1x, c1t);
    k_final<<<dim3(P_TOT / 256), dim3(256), 0, stream>>>(sA, wA, c0x, c0t, c1x, c1t,
                                                         out, partial);
    k_entropy<<<1, 128, 0, stream>>>(partial, out);
}

// Round 3
// 620.684 us; speedup vs baseline: 1.2608x; 1.0953x over previous
//
#include <hip/hip_runtime.h>
#include <math.h>

#define T_CLS 4096
#define V_SZ  4096
#define FW    5
#define S_LEN 512
#define P_TOT 32768          // B*S = 64*512
#define WROW  20480          // V_SZ * FW floats = 80 KB per t-row
#define TT    64             // t's per chunk (per block)
#define NCH   (T_CLS / TT)   // 64 chunks
#define NPC   4              // position chunks
#define PPB   (P_TOT / NPC)  // 8192 positions per block
#define THR   1024           // 16 waves -> 4 waves/SIMD (latency hiding)
#define PPT   8              // positions per thread (8 | 512: no row crossing)
#define NWIN  (PPT + 4)      // sliding-window slots
// half-ulp of lse (lse in [8,16) -> ulp 2^-20): fp32 log_softmax tie band
#define HALF_ULP 4.76837158203125e-7

typedef const __attribute__((address_space(1))) void* gas_t;
typedef __attribute__((address_space(3))) void* las_t;

// =====================================================================
// fused kernel: gather-logits + online sum-exp + top-2, no logits buffer.
// LDS double buffer, split layout per buffer b (byte base b*81920):
//   [0,65536)      float4 table: entry v at v*16 = W[t][v][0..3]
//   [65536,81920)  scalar table: entry v at v*4  = W[t][v][4]
// 2 x 80KB = 163840 B = exactly 160 KiB -> 1 block/CU, 16 waves resident
// (4 waves/SIMD; the 512-thread version had only 2 and was latency-bound).
// Each thread owns 8 contiguous positions, sliding 5-token window,
// 2 LDS ops per token. Padding handled by x{0,1} flags on the 4
// compile-time edge slots (exact +0.0 like numpy). t-accumulation order
// identical to previous version -> bit-identical results.
// =====================================================================
__global__ __launch_bounds__(THR) void k_fused(
    const float* __restrict__ W, const float* __restrict__ bias,
    const int* __restrict__ tok,
    float* __restrict__ sA, float* __restrict__ wA,
    float* __restrict__ c0xA, int* __restrict__ c0tA,
    float* __restrict__ c1xA, int* __restrict__ c1tA) {
    __shared__ __align__(16) float lds[40960];          // 163840 B
    char* ldsc = (char*)lds;
    const int tid = threadIdx.x;
    const int chunk = blockIdx.x;
    const int t0 = chunk * TT;
    const int p0 = blockIdx.y * PPB + tid * PPT;
    const int s0 = p0 & (S_LEN - 1);
    const int tokbase = p0 - s0;

    // per-thread window token offsets (bytes into f4 table), once
    int voff[NWIN];
#pragma unroll
    for (int idx = 0; idx < NWIN; ++idx) {
        const int j = s0 - 2 + idx;
        const int jc = min(max(j, 0), S_LEN - 1);
        voff[idx] = tok[tokbase + jc] << 4;
    }
    const float fa = (s0 == 0) ? 0.0f : 1.0f;              // idx 0,1 invalid
    const float fb = (s0 == S_LEN - PPT) ? 0.0f : 1.0f;    // idx NWIN-2,NWIN-1 invalid

    float sAcc[PPT], wAcc[PPT], c0x[PPT], c1x[PPT];
    int c0t[PPT], c1t[PPT];
#pragma unroll
    for (int o = 0; o < PPT; ++o) {
        sAcc[o] = 0.f; wAcc[o] = 0.f;
        c0x[o] = -INFINITY; c1x[o] = -INFINITY;
        c0t[o] = 0x7fffffff; c1t[o] = 0x7fffffff;
    }

    // prologue: stage row t0 into buffer 0 (4096 entries, 4 per thread)
    {
        const char* row = (const char*)(W + (size_t)t0 * WROW);
#pragma unroll
        for (int j = 0; j < 4; ++j) {
            const int l = j * THR + tid;
            __builtin_amdgcn_global_load_lds((gas_t)(row + 20 * l),
                                             (las_t)(ldsc + 16 * l), 16, 0, 0);
        }
#pragma unroll
        for (int j = 0; j < 4; ++j) {
            const int l = j * THR + tid;
            __builtin_amdgcn_global_load_lds((gas_t)(row + 20 * l + 16),
                                             (las_t)(ldsc + 65536 + 4 * l), 4, 0, 0);
        }
    }
    asm volatile("s_waitcnt vmcnt(0)" ::: "memory");
    __syncthreads();

    for (int i = 0; i < TT; ++i) {
        // issue async stage of next row into the other buffer
        if (i + 1 < TT) {
            const int bb = ((i + 1) & 1) * 81920;
            const char* row = (const char*)(W + (size_t)(t0 + i + 1) * WROW);
#pragma unroll
            for (int j = 0; j < 4; ++j) {
                const int l = j * THR + tid;
                __builtin_amdgcn_global_load_lds((gas_t)(row + 20 * l),
                                                 (las_t)(ldsc + bb + 16 * l), 16, 0, 0);
            }
#pragma unroll
            for (int j = 0; j < 4; ++j) {
                const int l = j * THR + tid;
                __builtin_amdgcn_global_load_lds((gas_t)(row + 20 * l + 16),
                                                 (las_t)(ldsc + bb + 65536 + 4 * l), 4, 0, 0);
            }
        }
        const int fb4 = (i & 1) * 81920;
        const int fbS = fb4 + 65536;
        const int tg = t0 + i;
        const float bt = bias[tg];

        float win[5][5];                                 // rotating token window
#pragma unroll
        for (int idx = 0; idx < NWIN; ++idx) {
            const float4 a = *(const float4*)(ldsc + fb4 + voff[idx]);
            float e4 = *(const float*)(ldsc + fbS + (voff[idx] >> 2));
            float ax = a.x, ay = a.y, az = a.z, aw = a.w;
            if (idx < 2)        { ax *= fa; ay *= fa; az *= fa; aw *= fa; e4 *= fa; }
            if (idx >= NWIN - 2){ ax *= fb; ay *= fb; az *= fb; aw *= fb; e4 *= fb; }
#pragma unroll
            for (int s = 0; s < 4; ++s) {
                win[s][0] = win[s+1][0]; win[s][1] = win[s+1][1];
                win[s][2] = win[s+1][2]; win[s][3] = win[s+1][3];
                win[s][4] = win[s+1][4];
            }
            win[4][0] = ax; win[4][1] = ay; win[4][2] = az;
            win[4][3] = aw; win[4][4] = e4;
            if (idx >= 4) {
                // numpy-exact order: b + k0 + k1 + k2 + k3 + k4
                float acc = bt;
                acc += win[0][0]; acc += win[1][1]; acc += win[2][2];
                acc += win[3][3]; acc += win[4][4];
                const int o = idx - 4;
                const float e = __expf(acc);
                sAcc[o] += e;
                wAcc[o] = fmaf(e, acc, wAcc[o]);
                if (acc > c0x[o])      { c1x[o] = c0x[o]; c1t[o] = c0t[o];
                                         c0x[o] = acc;    c0t[o] = tg; }
                else if (acc > c1x[o]) { c1x[o] = acc;    c1t[o] = tg; }
            }
        }
        asm volatile("s_waitcnt vmcnt(0)" ::: "memory");
        __syncthreads();
    }

    // write per-(chunk, position) online state, coalesced float4
    const size_t i0 = (size_t)chunk * P_TOT + p0;
#pragma unroll
    for (int q = 0; q < PPT / 4; ++q) {
        *(float4*)(sA  + i0 + 4*q) = make_float4(sAcc[4*q], sAcc[4*q+1], sAcc[4*q+2], sAcc[4*q+3]);
        *(float4*)(wA  + i0 + 4*q) = make_float4(wAcc[4*q], wAcc[4*q+1], wAcc[4*q+2], wAcc[4*q+3]);
        *(float4*)(c0xA + i0 + 4*q) = make_float4(c0x[4*q], c0x[4*q+1], c0x[4*q+2], c0x[4*q+3]);
        *(int4*)(c0tA + i0 + 4*q)   = make_int4(c0t[4*q], c0t[4*q+1], c0t[4*q+2], c0t[4*q+3]);
        *(float4*)(c1xA + i0 + 4*q) = make_float4(c1x[4*q], c1x[4*q+1], c1x[4*q+2], c1x[4*q+3]);
        *(int4*)(c1tA + i0 + 4*q)   = make_int4(c1t[4*q], c1t[4*q+1], c1t[4*q+2], c1t[4*q+3]);
    }
}

// =====================================================================
// merge chunks, band argmax, outputs, partial entropy
// 256 blocks x 128 threads -> all CUs participate
// =====================================================================
#define FIN_BLK 256
#define FIN_THR 128
__global__ __launch_bounds__(FIN_THR) void k_final(const float* __restrict__ sA,
                                               const float* __restrict__ wA,
                                               const float* __restrict__ c0xA,
                                               const int* __restrict__ c0tA,
                                               const float* __restrict__ c1xA,
                                               const int* __restrict__ c1tA,
                                               float* __restrict__ out,
                                               float* __restrict__ partial) {
    const int p = blockIdx.x * FIN_THR + threadIdx.x;
    float S = 0.f, Wm = 0.f, m = -INFINITY;
#pragma unroll 4
    for (int g = 0; g < NCH; g++) {
        const int i = g * P_TOT + p;
        S += sA[i]; Wm += wA[i];
        m = fmaxf(m, c0xA[i]);
    }
    int am = 0x7fffffff; float xam = m;
#pragma unroll 4
    for (int g = 0; g < NCH; g++) {
        const int i = g * P_TOT + p;
        const float x0 = c0xA[i]; const int t0c = c0tA[i];
        if ((double)m - (double)x0 < HALF_ULP && t0c < am) { am = t0c; xam = x0; }
        const float x1 = c1xA[i]; const int t1c = c1tA[i];
        if ((double)m - (double)x1 < HALF_ULP && t1c < am) { am = t1c; xam = x1; }
    }
    const float ls = logf(S);
    out[p] = (float)am;
    out[P_TOT + p] = xam - ls;          // log_softmax at argmax
    const float H = ls - Wm / S;        // per-position entropy

    __shared__ float red[FIN_THR];
    red[threadIdx.x] = H;
    __syncthreads();
    for (int off = FIN_THR / 2; off > 0; off >>= 1) {
        if (threadIdx.x < off) red[threadIdx.x] += red[threadIdx.x + off];
        __syncthreads();
    }
    if (threadIdx.x == 0) partial[blockIdx.x] = red[0];
}

__global__ __launch_bounds__(FIN_BLK) void k_entropy(const float* __restrict__ partial,
                                                 float* __restrict__ out) {
    __shared__ float red[FIN_BLK];
    red[threadIdx.x] = partial[threadIdx.x];
    __syncthreads();
    for (int off = FIN_BLK / 2; off > 0; off >>= 1) {
        if (threadIdx.x < off) red[threadIdx.x] += red[threadIdx.x + off];
        __syncthreads();
    }
    if (threadIdx.x == 0)
        out[2 * P_TOT] = red[0] / ((float)P_TOT * (float)T_CLS);
}

// ---------------- fallback (tiny workspace) ----------------------------------
__global__ void k_zero1(float* p) { *p = 0.0f; }
__global__ void k_scale1(float* p) { *p = *p / ((float)P_TOT * (float)T_CLS); }

__device__ inline void cand_init(float* cx, int* ct) {
#pragma unroll
    for (int j = 0; j < 4; j++) { cx[j] = -INFINITY; ct[j] = 0x7fffffff; }
}
__device__ inline void cand_insert(float* cx, int* ct, float x, int t) {
    if (!(x > cx[3])) return;
    if (x > cx[0]) {
        cx[3]=cx[2]; ct[3]=ct[2]; cx[2]=cx[1]; ct[2]=ct[1];
        cx[1]=cx[0]; ct[1]=ct[0]; cx[0]=x; ct[0]=t;
    } else if (x > cx[1]) {
        cx[3]=cx[2]; ct[3]=ct[2]; cx[2]=cx[1]; ct[2]=ct[1]; cx[1]=x; ct[1]=t;
    } else if (x > cx[2]) {
        cx[3]=cx[2]; ct[3]=ct[2]; cx[2]=x; ct[2]=t;
    } else { cx[3]=x; ct[3]=t; }
}
__device__ inline void cand_merge(float* ax, int* at, const float* bx, const int* bt) {
    float rx[4]; int rt[4]; int i = 0, j = 0;
#pragma unroll
    for (int k = 0; k < 4; k++) {
        const bool ta = (ax[i] > bx[j]) || (ax[i] == bx[j] && at[i] < bt[j]);
        if (ta) { rx[k] = ax[i]; rt[k] = at[i]; i++; }
        else    { rx[k] = bx[j]; rt[k] = bt[j]; j++; }
    }
#pragma unroll
    for (int k = 0; k < 4; k++) { ax[k] = rx[k]; at[k] = rt[k]; }
}
__device__ inline int band_argmax(const float* cx, const int* ct) {
    const double m = (double)cx[0];
    int am = ct[0];
#pragma unroll
    for (int j = 1; j < 4; j++)
        if (m - (double)cx[j] < HALF_ULP && ct[j] < am) am = ct[j];
    return am;
}

__global__ __launch_bounds__(64) void k_fallback(const float* __restrict__ W,
                                                 const float* __restrict__ bias,
                                                 const int* __restrict__ tok,
                                                 float* __restrict__ out) {
    const int p = blockIdx.x;
    const int srow = p & (S_LEN - 1);
    const int rowbase = p - srow;
    int vtok[FW]; bool val[FW];
#pragma unroll
    for (int k = 0; k < FW; k++) {
        const int ss = srow + k - 2;
        val[k] = ((unsigned)ss < (unsigned)S_LEN);
        vtok[k] = val[k] ? tok[rowbase + ss] : 0;
    }
    float s = 0.f, w = 0.f, cx[4]; int ct[4];
    cand_init(cx, ct);
    for (int t = threadIdx.x; t < T_CLS; t += 64) {
        const float* wr = W + (size_t)t * WROW;
        float acc = bias[t];
#pragma unroll
        for (int k = 0; k < FW; k++)
            if (val[k]) acc += wr[vtok[k] * FW + k];
        const float e = __expf(acc);
        s += e; w = fmaf(e, acc, w);
        cand_insert(cx, ct, acc, t);
    }
    for (int off = 32; off > 0; off >>= 1) {
        float ox[4]; int ot[4];
#pragma unroll
        for (int j = 0; j < 4; j++) { ox[j] = __shfl_down(cx[j], off); ot[j] = __shfl_down(ct[j], off); }
        const float os = __shfl_down(s, off);
        const float ow = __shfl_down(w, off);
        cand_merge(cx, ct, ox, ot);
        s += os; w += ow;
    }
    if (threadIdx.x == 0) {
        const int am = band_argmax(cx, ct);
        const float ls = logf(s);
        out[p] = (float)am;
        out[P_TOT + p] = cx[0] - ls;
        atomicAdd(&out[2 * P_TOT], ls - w / s);
    }
}

extern "C" void kernel_launch(void* const* d_in, const int* in_sizes, int n_in,
                              void* d_out, int out_size, void* d_ws, size_t ws_size,
                              hipStream_t stream) {
    const float* W    = (const float*)d_in[0];
    const float* bias = (const float*)d_in[1];
    const int*   tok  = (const int*)d_in[2];
    float* out = (float*)d_out;

    const size_t NS = (size_t)NCH * P_TOT;            // 2M entries per array
    const size_t stateBytes = NS * 4 * 6;             // s,w,c0x,c0t,c1x,c1t = 48 MB
    const size_t partialBytes = 1024 * 4;

    if (ws_size < stateBytes + partialBytes) {
        k_zero1<<<1, 1, 0, stream>>>(out + 2 * P_TOT);
        k_fallback<<<dim3(P_TOT), dim3(64), 0, stream>>>(W, bias, tok, out);
        k_scale1<<<1, 1, 0, stream>>>(out + 2 * P_TOT);
        return;
    }

    float* sA  = (float*)d_ws;
    float* wA  = sA + NS;
    float* c0x = wA + NS;
    int*   c0t = (int*)(c0x + NS);
    float* c1x = (float*)(c0t + NS);
    int*   c1t = (int*)(c1x + NS);
    float* partial = (float*)(c1t + NS);

    // grid: x = t-chunk (64), y = p-chunk (4). 256 blocks = 1/CU, one round.
    // Siblings of a t-chunk are 64 apart in linear id -> same id%8 -> same XCD
    // -> W row fetched from HBM once, siblings hit L2/L3.
    k_fused<<<dim3(NCH, NPC), dim3(THR), 0, stream>>>(W, bias, tok,
                                                      sA, wA, c0x, c0t, c1x, c1t);
    k_final<<<dim3(FIN_BLK), dim3(FIN_THR), 0, stream>>>(sA, wA, c0x, c0t, c1x, c1t,
                                                         out, partial);
    k_entropy<<<1, FIN_BLK, 0, stream>>>(partial, out);
}